// Round 1
// baseline (749.870 us; speedup 1.0000x reference)
//
#include <hip/hip_runtime.h>
#include <math.h>

// ---------------------------------------------------------------------------
// GCN-VAE forward for MI355X.
// Pipeline:
//   deg/dinv -> CSR(dst) build -> GEMM1(gather emb[x] @ W1) -> agg1(+b1,relu)
//   -> GEMM2(@W2) -> agg2(+b2,relu) -> GEMM mu / GEMM logvar -> z reparam
//   -> GEMM3(relu z@W3+b3) -> GEMM4(t@W4+b4 -> recon) -> cap sigmoid dot
// No float atomics anywhere; aggregation is CSR wave-per-node with float4.
// ---------------------------------------------------------------------------

__global__ __launch_bounds__(256) void k_init(int* __restrict__ degint,
                                              int* __restrict__ cursor, int N) {
    int i = blockIdx.x * 256 + threadIdx.x;
    if (i < N) { degint[i] = 1; cursor[i] = 0; }   // 1 = self-loop
}

__global__ __launch_bounds__(256) void k_deg_count(const int* __restrict__ dst,
                                                   int* __restrict__ degint, int E) {
    int e = blockIdx.x * 256 + threadIdx.x;
    if (e < E) atomicAdd(&degint[dst[e]], 1);
}

__global__ __launch_bounds__(256) void k_dinv(const int* __restrict__ degint,
                                              float* __restrict__ dinv, int N) {
    int i = blockIdx.x * 256 + threadIdx.x;
    if (i < N) dinv[i] = rsqrtf((float)degint[i]);
}

// ---- 3-kernel exclusive scan of (degint[i]-1) -> row_ptr -------------------
#define SCAN_BLOCK 1024
__global__ __launch_bounds__(SCAN_BLOCK) void k_scan_local(
        const int* __restrict__ degint, int* __restrict__ row_ptr,
        int* __restrict__ bsum, int N) {
    __shared__ int s[SCAN_BLOCK];
    int gid = blockIdx.x * SCAN_BLOCK + threadIdx.x;
    int v = (gid < N) ? (degint[gid] - 1) : 0;
    s[threadIdx.x] = v;
    __syncthreads();
    for (int off = 1; off < SCAN_BLOCK; off <<= 1) {
        int t = (threadIdx.x >= off) ? s[threadIdx.x - off] : 0;
        __syncthreads();
        s[threadIdx.x] += t;
        __syncthreads();
    }
    if (gid < N) row_ptr[gid] = s[threadIdx.x] - v;          // exclusive
    if (threadIdx.x == SCAN_BLOCK - 1) bsum[blockIdx.x] = s[SCAN_BLOCK - 1];
}

__global__ void k_scan_bsum(int* __restrict__ bsum, int nb) {
    if (blockIdx.x == 0 && threadIdx.x == 0) {
        int acc = 0;
        for (int i = 0; i < nb; ++i) { int v = bsum[i]; bsum[i] = acc; acc += v; }
    }
}

__global__ __launch_bounds__(256) void k_scan_add(int* __restrict__ row_ptr,
                                                  const int* __restrict__ bsum,
                                                  int N, int E) {
    int gid = blockIdx.x * 256 + threadIdx.x;
    if (gid < N) row_ptr[gid] += bsum[gid / SCAN_BLOCK];
    if (gid == 0) row_ptr[N] = E;
}

__global__ __launch_bounds__(256) void k_csr_fill(
        const int* __restrict__ src, const int* __restrict__ dst,
        const int* __restrict__ row_ptr, int* __restrict__ cursor,
        int* __restrict__ csr_src, int E) {
    int e = blockIdx.x * 256 + threadIdx.x;
    if (e < E) {
        int d = dst[e];
        int pos = atomicAdd(&cursor[d], 1);
        csr_src[row_ptr[d] + pos] = src[e];
    }
}

// ---- tiled fp32 GEMM: C[M,Ncol] = A[M,K] @ B[K,Ncol] (+bias)(relu) ---------
// BM=BN=64, BK=16, 256 threads, 4x4 microtile per thread. GATHER: A row r is
// Afull[idx[r]] (embedding lookup fusion).
template<bool GATHER, bool RELU, bool BIAS>
__global__ __launch_bounds__(256) void k_gemm(
        const float* __restrict__ A, const int* __restrict__ idx,
        const float* __restrict__ B, const float* __restrict__ bias,
        float* __restrict__ C, int M, int K, int Ncol) {
    constexpr int BM = 64, BN = 64, BK = 16;
    __shared__ float As[BK][BM];   // transposed A tile
    __shared__ float Bs[BK][BN];
    const int tid = threadIdx.x;
    const int tx = tid & 15, ty = tid >> 4;
    const int rowBase = blockIdx.x * BM;
    const int colBase = blockIdx.y * BN;
    const int lr = tid >> 2, lc4 = tid & 3;   // A tile: 64 rows x 4 float4
    const int br = tid >> 4, bc4 = tid & 15;  // B tile: 16 rows x 16 float4
    const int arow = rowBase + lr;
    int asrc = arow;
    if (GATHER) asrc = (arow < M) ? idx[arow] : 0;
    const int K4 = K >> 2, N4 = Ncol >> 2;
    const float4* A4 = (const float4*)A;
    const float4* B4 = (const float4*)B;
    float acc[4][4] = {{0.f}};
    for (int k0 = 0; k0 < K; k0 += BK) {
        float4 av = make_float4(0.f, 0.f, 0.f, 0.f);
        if (arow < M) av = A4[(long)asrc * K4 + (k0 >> 2) + lc4];
        As[lc4 * 4 + 0][lr] = av.x;
        As[lc4 * 4 + 1][lr] = av.y;
        As[lc4 * 4 + 2][lr] = av.z;
        As[lc4 * 4 + 3][lr] = av.w;
        float4 bv = B4[(long)(k0 + br) * N4 + (colBase >> 2) + bc4];
        *(float4*)&Bs[br][bc4 * 4] = bv;
        __syncthreads();
#pragma unroll
        for (int k = 0; k < BK; ++k) {
            float4 a4v = *(const float4*)&As[k][ty * 4];
            float4 b4v = *(const float4*)&Bs[k][tx * 4];
            float aa[4] = {a4v.x, a4v.y, a4v.z, a4v.w};
            float bb[4] = {b4v.x, b4v.y, b4v.z, b4v.w};
#pragma unroll
            for (int i = 0; i < 4; ++i)
#pragma unroll
                for (int j = 0; j < 4; ++j)
                    acc[i][j] = fmaf(aa[i], bb[j], acc[i][j]);
        }
        __syncthreads();
    }
    float4 bb4 = make_float4(0.f, 0.f, 0.f, 0.f);
    if (BIAS) bb4 = ((const float4*)bias)[(colBase >> 2) + tx];
#pragma unroll
    for (int i = 0; i < 4; ++i) {
        int row = rowBase + ty * 4 + i;
        if (row < M) {
            float4 o;
            o.x = acc[i][0] + bb4.x; o.y = acc[i][1] + bb4.y;
            o.z = acc[i][2] + bb4.z; o.w = acc[i][3] + bb4.w;
            if (RELU) {
                o.x = fmaxf(o.x, 0.f); o.y = fmaxf(o.y, 0.f);
                o.z = fmaxf(o.z, 0.f); o.w = fmaxf(o.w, 0.f);
            }
            ((float4*)C)[(long)row * N4 + (colBase >> 2) + tx] = o;
        }
    }
}

// ---- CSR aggregation: out[i] = relu(b + sum_e hW[src_e]*dinv[s]*dinv[i]
//                                       + hW[i]*dinv[i]^2), 256 feats --------
// One wave (64 lanes) per node, float4 per lane. Block = 4 waves.
__global__ __launch_bounds__(256) void k_agg(
        const float* __restrict__ hW, const int* __restrict__ row_ptr,
        const int* __restrict__ csr_src, const float* __restrict__ dinv,
        const float* __restrict__ bias, float* __restrict__ out, int N) {
    const int wave = threadIdx.x >> 6;
    const int lane = threadIdx.x & 63;
    const int node = blockIdx.x * 4 + wave;
    if (node >= N) return;
    const float4* hw4 = (const float4*)hW;
    const float di = dinv[node];
    const float selfw = di * di;
    float4 a = hw4[(long)node * 64 + lane];
    float4 acc;
    acc.x = a.x * selfw; acc.y = a.y * selfw;
    acc.z = a.z * selfw; acc.w = a.w * selfw;
    const int beg = row_ptr[node], end = row_ptr[node + 1];
    for (int e = beg; e < end; ++e) {
        int s = csr_src[e];
        float w = dinv[s] * di;
        float4 v = hw4[(long)s * 64 + lane];
        acc.x = fmaf(v.x, w, acc.x); acc.y = fmaf(v.y, w, acc.y);
        acc.z = fmaf(v.z, w, acc.z); acc.w = fmaf(v.w, w, acc.w);
    }
    float4 b = ((const float4*)bias)[lane];
    acc.x = fmaxf(acc.x + b.x, 0.f); acc.y = fmaxf(acc.y + b.y, 0.f);
    acc.z = fmaxf(acc.z + b.z, 0.f); acc.w = fmaxf(acc.w + b.w, 0.f);
    ((float4*)out)[(long)node * 64 + lane] = acc;
}

// ---- z = mu + eps * exp(0.5*logvar) ---------------------------------------
__global__ __launch_bounds__(256) void k_z(
        const float* __restrict__ mu, const float* __restrict__ lv,
        const float* __restrict__ eps, float* __restrict__ z, int n) {
    int i = blockIdx.x * 256 + threadIdx.x;
    if (i < n) z[i] = fmaf(eps[i], expf(0.5f * lv[i]), mu[i]);
}

// ---- capitalize = sigmoid(z @ Wcap + bcap); wave-per-node dot of length 64 -
__global__ __launch_bounds__(256) void k_cap(
        const float* __restrict__ z, const float* __restrict__ Wcap,
        const float* __restrict__ bcap, float* __restrict__ out, int N) {
    const int wave = threadIdx.x >> 6;
    const int lane = threadIdx.x & 63;
    const int node = blockIdx.x * 4 + wave;
    if (node >= N) return;
    float v = z[(long)node * 64 + lane] * Wcap[lane];
    for (int off = 32; off; off >>= 1) v += __shfl_down(v, off, 64);
    if (lane == 0) out[node] = 1.f / (1.f + expf(-(v + bcap[0])));
}

extern "C" void kernel_launch(void* const* d_in, const int* in_sizes, int n_in,
                              void* d_out, int out_size, void* d_ws, size_t ws_size,
                              hipStream_t stream) {
    const int*   x    = (const int*)d_in[0];
    const int*   ei   = (const int*)d_in[1];
    const float* eps  = (const float*)d_in[2];
    const float* emb  = (const float*)d_in[3];
    const float* W1   = (const float*)d_in[4];
    const float* b1   = (const float*)d_in[5];
    const float* W2   = (const float*)d_in[6];
    const float* b2   = (const float*)d_in[7];
    const float* Wmu  = (const float*)d_in[8];
    const float* bmu  = (const float*)d_in[9];
    const float* Wlv  = (const float*)d_in[10];
    const float* blv  = (const float*)d_in[11];
    const float* W3   = (const float*)d_in[12];
    const float* b3   = (const float*)d_in[13];
    const float* W4   = (const float*)d_in[14];
    const float* b4   = (const float*)d_in[15];
    const float* Wcap = (const float*)d_in[16];
    const float* bcap = (const float*)d_in[17];

    const int N = in_sizes[0];
    const int E = in_sizes[1] / 2;
    const int H = in_sizes[5];            // 256
    const int L = in_sizes[9];            // 64
    const int V = in_sizes[15];           // 128
    const int F = in_sizes[4] / H;        // 128

    const int* src = ei;
    const int* dst = ei + E;

    // ---- workspace carve-up ----
    char* w = (char*)d_ws;
    float* bufA   = (float*)w; w += (size_t)N * H * 4;       // hW1 / hW2 / z
    float* bufB   = (float*)w; w += (size_t)N * H * 4;       // h1 / h2 / t
    int*   degint = (int*)w;   w += (size_t)N * 4;
    int*   rowp   = (int*)w;   w += (size_t)(N + 1) * 4;
    int*   cursor = (int*)w;   w += (size_t)N * 4;
    float* dinv   = (float*)w; w += (size_t)N * 4;
    int*   bsum   = (int*)w;   w += 256 * 4;
    int*   csrsrc = (int*)w;   w += (size_t)E * 4;

    float* outp    = (float*)d_out;
    float* recon   = outp;                               // [N, V]
    float* cap     = outp + (size_t)N * V;               // [N, 1]
    float* mu      = outp + (size_t)N * V + N;           // [N, L]
    float* logvar  = mu + (size_t)N * L;                 // [N, L]
    float* z       = bufA;                               // [N, L] (overlays hW2 slot)

    const int nN  = (N + 255) / 256;
    const int nE  = (E + 255) / 256;
    const int nSc = (N + SCAN_BLOCK - 1) / SCAN_BLOCK;
    const int gM  = (N + 63) / 64;

    // ---- degree / dinv / CSR ----
    k_init<<<nN, 256, 0, stream>>>(degint, cursor, N);
    k_deg_count<<<nE, 256, 0, stream>>>(dst, degint, E);
    k_dinv<<<nN, 256, 0, stream>>>(degint, dinv, N);
    k_scan_local<<<nSc, SCAN_BLOCK, 0, stream>>>(degint, rowp, bsum, N);
    k_scan_bsum<<<1, 64, 0, stream>>>(bsum, nSc);
    k_scan_add<<<nN, 256, 0, stream>>>(rowp, bsum, N, E);
    k_csr_fill<<<nE, 256, 0, stream>>>(src, dst, rowp, cursor, csrsrc, E);

    // ---- conv1: hW1 = emb[x] @ W1 ; h1 = relu(agg + b1) ----
    k_gemm<true,  false, false><<<dim3(gM, H / 64), 256, 0, stream>>>(
        emb, x, W1, nullptr, bufA, N, F, H);
    k_agg<<<(N + 3) / 4, 256, 0, stream>>>(bufA, rowp, csrsrc, dinv, b1, bufB, N);

    // ---- conv2: hW2 = h1 @ W2 ; h2 = relu(agg + b2) ----
    k_gemm<false, false, false><<<dim3(gM, H / 64), 256, 0, stream>>>(
        bufB, nullptr, W2, nullptr, bufA, N, H, H);
    k_agg<<<(N + 3) / 4, 256, 0, stream>>>(bufA, rowp, csrsrc, dinv, b2, bufB, N);

    // ---- heads: mu, logvar ----
    k_gemm<false, false, true><<<dim3(gM, L / 64), 256, 0, stream>>>(
        bufB, nullptr, Wmu, bmu, mu, N, H, L);
    k_gemm<false, false, true><<<dim3(gM, L / 64), 256, 0, stream>>>(
        bufB, nullptr, Wlv, blv, logvar, N, H, L);

    // ---- reparameterize ----
    k_z<<<(N * L + 255) / 256, 256, 0, stream>>>(mu, logvar, eps, z, N * L);

    // ---- decode: t = relu(z@W3+b3); recon = t@W4+b4 ----
    k_gemm<false, true,  true><<<dim3(gM, H / 64), 256, 0, stream>>>(
        z, nullptr, W3, b3, bufB, N, L, H);
    k_gemm<false, false, true><<<dim3(gM, V / 64), 256, 0, stream>>>(
        bufB, nullptr, W4, b4, recon, N, H, V);

    // ---- capitalize head ----
    k_cap<<<(N + 3) / 4, 256, 0, stream>>>(z, Wcap, bcap, cap, N);
}